// Round 1
// baseline (348.730 us; speedup 1.0000x reference)
//
#include <hip/hip_runtime.h>
#include <cstdint>
#include <cstddef>

typedef unsigned int u32;
typedef unsigned short u16;
typedef __attribute__((ext_vector_type(8))) short bf16x8;   // 8 bf16 = 4 VGPR
typedef __attribute__((ext_vector_type(4))) float f32x4;

#define DEV __device__ __forceinline__

DEV float b2f(u16 u){ return __uint_as_float(((u32)u)<<16); }
DEV u16 f2b(float f){ u32 x = __float_as_uint(f); x += 0x7fffu + ((x>>16)&1u); return (u16)(x>>16); }

DEV void gll16(const void* g, void* l){
  __builtin_amdgcn_global_load_lds((const __attribute__((address_space(1))) u32*)g,
                                   (__attribute__((address_space(3))) u32*)l, 16, 0, 0);
}

// token row -> (window, in-window index);  H=W=D=32, g=8
DEV void win_n(int r, int& win, int& n){
  int d_ = r & 31, w_ = (r>>5)&31, h_ = r>>10;
  win = ((h_>>3)<<4) | ((w_>>3)<<2) | (d_>>3);
  n   = ((h_&7)<<6)  | ((w_&7)<<3)  | (d_&7);
}
// window-order row -> token row
DEV int tok_of(int r){
  int win = r>>9, nn = r&511;
  int bh = win>>4, bw=(win>>2)&3, bd=win&3;
  int ih = nn>>6,  iw=(nn>>3)&7,  id=nn&7;
  return ((bh*8+ih)<<10) | ((bw*8+iw)<<5) | (bd*8+id);
}

// ---------------- small prep kernels ----------------

// dst bf16 [N][K] = transpose(src fp32 [K][N])
__global__ void wtr_k(const float* __restrict__ w, u16* __restrict__ wt, int K, int N){
  int f = blockIdx.x*256 + threadIdx.x;
  if (f >= K*N) return;
  int n = f / K, k = f - n*K;
  wt[f] = f2b(w[(size_t)k*N + n]);
}

__global__ void conv_k(const float* __restrict__ x, u16* __restrict__ o, int n4){
  int stride = gridDim.x*blockDim.x;
  for (int i = blockIdx.x*blockDim.x + threadIdx.x; i < n4; i += stride){
    const float4 v = *(const float4*)(x + (size_t)i*4);
    u32 lo = (u32)f2b(v.x) | ((u32)f2b(v.y)<<16);
    u32 hi = (u32)f2b(v.z) | ((u32)f2b(v.w)<<16);
    *(uint2*)(o + (size_t)i*4) = make_uint2(lo, hi);
  }
}

// LayerNorm over 256 cols, one wave per row, writes bf16
__global__ __launch_bounds__(256)
void ln_k(const float* __restrict__ x, const float* __restrict__ g,
          const float* __restrict__ b, u16* __restrict__ out){
  int row  = blockIdx.x*4 + (threadIdx.x>>6);
  int lane = threadIdx.x & 63;
  const float4 v = *(const float4*)(x + (size_t)row*256 + lane*4);
  float s = v.x+v.y+v.z+v.w;
  #pragma unroll
  for (int m=1;m<64;m<<=1) s += __shfl_xor(s, m);
  float mean = s * (1.0f/256.0f);
  float d0=v.x-mean,d1=v.y-mean,d2=v.z-mean,d3=v.w-mean;
  float q = d0*d0+d1*d1+d2*d2+d3*d3;
  #pragma unroll
  for (int m=1;m<64;m<<=1) q += __shfl_xor(q, m);
  float rs = rsqrtf(q*(1.0f/256.0f) + 1e-5f);
  const float4 gg = *(const float4*)(g + lane*4);
  const float4 bb = *(const float4*)(b + lane*4);
  u32 lo = (u32)f2b(d0*rs*gg.x+bb.x) | ((u32)f2b(d1*rs*gg.y+bb.y)<<16);
  u32 hi = (u32)f2b(d2*rs*gg.z+bb.z) | ((u32)f2b(d3*rs*gg.w+bb.w)<<16);
  *(uint2*)(out + (size_t)row*256 + lane*4) = make_uint2(lo,hi);
}

// position-bias MLP: one thread per table row (3375 rows)
template<int NOUT>
DEV void pstage(float* v, const float* g, const float* b, const float* W, const float* bb){
  float m = 0.f;
  #pragma unroll
  for (int i=0;i<16;i++) m += v[i];
  m *= 0.0625f;
  float q = 0.f;
  #pragma unroll
  for (int i=0;i<16;i++){ float d=v[i]-m; q += d*d; }
  float rs = rsqrtf(q*0.0625f + 1e-5f);
  float u[16];
  #pragma unroll
  for (int i=0;i<16;i++){ float t = (v[i]-m)*rs*g[i] + b[i]; u[i] = t>0.f?t:0.f; }
  #pragma unroll
  for (int o=0;o<NOUT;o++){
    float s = bb[o];
    #pragma unroll
    for (int kk=0;kk<16;kk++) s += u[kk]*W[kk*NOUT+o];
    v[o] = s;
  }
}

__global__ void posmlp_k(const float* pp_w, const float* pp_b,
                         const float* g1, const float* b1, const float* w1, const float* bb1,
                         const float* g2, const float* b2, const float* w2, const float* bb2,
                         const float* g3, const float* b3, const float* w3, const float* bb3,
                         float* __restrict__ pos){
  int i = blockIdx.x*256 + threadIdx.x;
  if (i >= 3375) return;
  int t = i;
  int bd = t % 15; t /= 15;
  int bw = t % 15; t /= 15;
  int bh = t;
  float fh = (float)(bh-7), fw = (float)(bw-7), fd = (float)(bd-7);
  float v[16];
  #pragma unroll
  for (int o=0;o<16;o++) v[o] = fh*pp_w[o] + fw*pp_w[16+o] + fd*pp_w[32+o] + pp_b[o];
  pstage<16>(v, g1,b1,w1,bb1);
  pstage<16>(v, g2,b2,w2,bb2);
  pstage<8> (v, g3,b3,w3,bb3);
  #pragma unroll
  for (int h=0;h<8;h++) pos[(size_t)i*8 + h] = v[h];
}

// expand bias into MFMA-fragment layout: biasF[h][qc(32)][nc(32)][lane(64)][j(4)], bf16
__global__ void biasx_k(const float* __restrict__ pos, u16* __restrict__ biasF){
  int f = blockIdx.x*256 + threadIdx.x;    // 2,097,152 total
  int j = f&3, ln = (f>>2)&63, nc = (f>>8)&31, qc = (f>>13)&31, h = f>>18;
  int q = qc*16 + ((ln>>4)<<2) + j;
  int k = nc*16 + (ln&15);
  int rh = (q>>6) - (k>>6) + 7;
  int rw = ((q>>3)&7) - ((k>>3)&7) + 7;
  int rd = (q&7) - (k&7) + 7;
  int idx = (rh*15 + rw)*15 + rd;
  biasF[f] = f2b(pos[idx*8 + h]);
}

// transpose V (per window-head) [512][32] -> [32][512]
__global__ __launch_bounds__(256)
void vtr_k(const u16* __restrict__ Vn, u16* __restrict__ Vt){
  __shared__ u16 lv[16384];
  int bid = blockIdx.x, tid = threadIdx.x;
  const u16* src = Vn + (size_t)bid*16384;
  #pragma unroll
  for (int r=0;r<8;r++){
    int off = (r*256 + tid)*16;
    gll16((const char*)src + off, (char*)lv + off);
  }
  __syncthreads();
  u16* dst = Vt + (size_t)bid*16384;
  #pragma unroll 4
  for (int i=0;i<64;i++){
    int f = i*256 + tid;               // f = d*512 + n
    dst[f] = lv[(f&511)*32 + (f>>9)];
  }
}

// ---------------- GEMM: C[M][·] = A[M][K](bf16) @ Bt[N][K](bf16)^T, per-mode epilogue ----------------
struct GemmP {
  const u16* A; const u16* Bt;
  int K;
  const float* bvec;
  float scale;
  const float* add32;
  float* out32;
  u16* out16;
  u16* out16b;
};

template<int MODE>
__global__ __launch_bounds__(256)
void gemm_k(GemmP p){
  __shared__ u16 lA[2][4096];
  __shared__ u16 lB[2][4096];
  const int tid = threadIdx.x;
  const int wid = tid>>6, lane = tid&63;
  const int lr = lane&15, lg = lane>>4;
  const int m0 = blockIdx.x*128, n0 = blockIdx.y*128;
  const int K = p.K;
  const int nt = K>>5;
  const int wm = (wid>>1)*64, wn = (wid&1)*64;
  const f32x4 z4 = {0.f,0.f,0.f,0.f};

  f32x4 acc[4][4];
  #pragma unroll
  for (int i=0;i<4;i++)
    #pragma unroll
    for (int j=0;j<4;j++) acc[i][j] = z4;

  // prologue stage (t = 0)
  #pragma unroll
  for (int r=0;r<2;r++){
    int off = (r*256 + tid)*16;
    int row = off>>6, kc = (off&63)>>1;
    gll16(p.A  + (size_t)(m0+row)*K + kc, (char*)lA[0] + off);
    gll16(p.Bt + (size_t)(n0+row)*K + kc, (char*)lB[0] + off);
  }
  __syncthreads();
  int cur = 0;
  for (int t=0; t<nt; ++t){
    if (t+1 < nt){
      int k0 = (t+1)<<5;
      #pragma unroll
      for (int r=0;r<2;r++){
        int off = (r*256 + tid)*16;
        int row = off>>6, kc = (off&63)>>1;
        gll16(p.A  + (size_t)(m0+row)*K + k0 + kc, (char*)lA[cur^1] + off);
        gll16(p.Bt + (size_t)(n0+row)*K + k0 + kc, (char*)lB[cur^1] + off);
      }
    }
    bf16x8 af[4], bfr[4];
    #pragma unroll
    for (int i=0;i<4;i++){
      af[i]  = *(const bf16x8*)&lA[cur][(wm + i*16 + lr)*32 + lg*8];
      bfr[i] = *(const bf16x8*)&lB[cur][(wn + i*16 + lr)*32 + lg*8];
    }
    #pragma unroll
    for (int i=0;i<4;i++)
      #pragma unroll
      for (int j=0;j<4;j++)
        acc[i][j] = __builtin_amdgcn_mfma_f32_16x16x32_bf16(af[i], bfr[j], acc[i][j], 0,0,0);
    __syncthreads();
    cur ^= 1;
  }

  // epilogue: D layout col=lane&15, row=(lane>>4)*4+v  [verified m89]
  #pragma unroll
  for (int i=0;i<4;i++){
    #pragma unroll
    for (int j=0;j<4;j++){
      #pragma unroll
      for (int v=0;v<4;v++){
        int r = m0 + wm + i*16 + lg*4 + v;
        int c = n0 + wn + j*16 + lr;
        float val = acc[i][j][v];
        if constexpr (MODE==0){           // Q: (val+b)*scale -> Q[win][h][n][d]
          float qv = (val + p.bvec[c]) * p.scale;
          int win, n; win_n(r, win, n);
          int hh = c>>5, dd = c&31;
          p.out16[((size_t)((win*8+hh)*512 + n)<<5) + dd] = f2b(qv);
        } else if constexpr (MODE==1){    // K (c<256) / V (c>=256), window layout
          float ov = val + p.bvec[c];
          int win, n; win_n(r, win, n);
          int cc = c & 255;
          int hh = cc>>5, dd = cc&31;
          size_t o = ((size_t)((win*8+hh)*512 + n)<<5) + dd;
          if (c < 256) p.out16[o] = f2b(ov); else p.out16b[o] = f2b(ov);
        } else if constexpr (MODE==2){    // proj + x residual, window row -> token row
          int l = tok_of(r);
          size_t o = (size_t)l*256 + c;
          p.out32[o] = val + p.bvec[c] + p.add32[o];
        } else if constexpr (MODE==3){    // fc1 + exact GELU
          float u = val + p.bvec[c];
          float ge = 0.5f*u*(1.0f + erff(u*0.70710678118654752f));
          p.out16[(size_t)r*1024 + c] = f2b(ge);
        } else {                          // fc2 + residual -> fp32 out
          size_t o = (size_t)r*256 + c;
          p.out32[o] = val + p.bvec[c] + p.add32[o];
        }
      }
    }
  }
}

// ---------------- attention: one block per (window, head) ----------------
__global__ __launch_bounds__(256)
void attn_k(const u16* __restrict__ Q, const u16* __restrict__ K,
            const u16* __restrict__ Vt, const u16* __restrict__ biasF,
            u16* __restrict__ out){
  __shared__ u16 lK[16384];      // K  [512 n][32 d]
  __shared__ u16 lV[16384];      // V^T[32 d][512 n]
  __shared__ u16 lP[4][512];     // per-wave P ping-pong [16 q][32 k]
  const int bid = blockIdx.x;
  const int win = bid>>3, hh = bid&7;
  const int tid = threadIdx.x, wid = tid>>6, lane = tid&63;
  const int lr = lane&15, lg = lane>>4;
  const u16* Kb = K  + (size_t)bid*16384;
  const u16* Vb = Vt + (size_t)bid*16384;
  const u16* Qb = Q  + (size_t)bid*16384;
  #pragma unroll
  for (int r=0;r<8;r++){
    int off = (r*256 + tid)*16;
    gll16((const char*)Kb + off, (char*)lK + off);
    gll16((const char*)Vb + off, (char*)lV + off);
  }
  __syncthreads();
  const u16* bF = biasF + ((size_t)hh<<18);
  const f32x4 z4 = {0.f,0.f,0.f,0.f};

  for (int ch=0; ch<8; ++ch){
    const int r0 = wid*128 + ch*16;
    const int qc = r0>>4;
    // Q fragment straight from global (coalesced 16B/lane)
    bf16x8 qf = *(const bf16x8*)(Qb + (size_t)(r0+lr)*32 + lg*8);
    // S = Q K^T  (full 512-wide row in registers: 32 frags)
    f32x4 sf[32];
    #pragma unroll
    for (int nc=0;nc<32;nc++){
      bf16x8 kf = *(const bf16x8*)&lK[(nc*16+lr)*32 + lg*8];
      sf[nc] = __builtin_amdgcn_mfma_f32_16x16x32_bf16(qf, kf, z4, 0,0,0);
    }
    // + bias (fragment-layout table, one 8B coalesced load per frag)
    const u16* bq = bF + ((size_t)qc<<13) + lane*4;
    #pragma unroll
    for (int nc=0;nc<32;nc++){
      uint2 bv = *(const uint2*)(bq + nc*256);
      sf[nc][0] += b2f((u16)(bv.x & 0xffffu));
      sf[nc][1] += b2f((u16)(bv.x >> 16));
      sf[nc][2] += b2f((u16)(bv.y & 0xffffu));
      sf[nc][3] += b2f((u16)(bv.y >> 16));
    }
    // full-row softmax (rows live in 16-lane groups)
    float mx[4], sm[4];
    #pragma unroll
    for (int v=0;v<4;v++){
      float m = -3.0e38f;
      #pragma unroll
      for (int nc=0;nc<32;nc++) m = fmaxf(m, sf[nc][v]);
      #pragma unroll
      for (int msk=1;msk<16;msk<<=1) m = fmaxf(m, __shfl_xor(m, msk));
      mx[v] = m;
    }
    #pragma unroll
    for (int nc=0;nc<32;nc++){
      #pragma unroll
      for (int v=0;v<4;v++) sf[nc][v] = __expf(sf[nc][v] - mx[v]);
    }
    #pragma unroll
    for (int v=0;v<4;v++){
      float s = 0.f;
      #pragma unroll
      for (int nc=0;nc<32;nc++) s += sf[nc][v];
      #pragma unroll
      for (int msk=1;msk<16;msk<<=1) s += __shfl_xor(s, msk);
      sm[v] = s;
    }
    // PV: repack P (D-layout) -> A-layout via per-wave LDS, accumulate O[16][32]
    f32x4 o0 = z4, o1 = z4;
    u16* pb = lP[wid];
    for (int kc=0;kc<16;kc++){
      #pragma unroll
      for (int t2=0;t2<2;t2++){
        int nc = kc*2+t2;
        #pragma unroll
        for (int v=0;v<4;v++)
          pb[(lg*4+v)*32 + t2*16 + lr] = f2b(sf[nc][v]);
      }
      bf16x8 pf = *(const bf16x8*)&pb[lr*32 + lg*8];
      bf16x8 v0 = *(const bf16x8*)&lV[(lr     )*512 + kc*32 + lg*8];
      bf16x8 v1 = *(const bf16x8*)&lV[(16 + lr)*512 + kc*32 + lg*8];
      o0 = __builtin_amdgcn_mfma_f32_16x16x32_bf16(pf, v0, o0, 0,0,0);
      o1 = __builtin_amdgcn_mfma_f32_16x16x32_bf16(pf, v1, o1, 0,0,0);
    }
    #pragma unroll
    for (int v=0;v<4;v++){
      float inv = 1.0f / sm[v];
      int n = r0 + lg*4 + v;
      size_t base = ((size_t)(win*512 + n))*256 + hh*32;
      out[base + lr]      = f2b(o0[v]*inv);
      out[base + 16 + lr] = f2b(o1[v]*inv);
    }
  }
}

// ---------------- host launch ----------------
extern "C" void kernel_launch(void* const* d_in, const int* in_sizes, int n_in,
                              void* d_out, int out_size, void* d_ws, size_t ws_size,
                              hipStream_t stream){
  const float* x      = (const float*)d_in[0];
  const float* y      = (const float*)d_in[1];
  const float* n1_g   = (const float*)d_in[2];
  const float* n1_b   = (const float*)d_in[3];
  const float* qkv_w  = (const float*)d_in[4];
  const float* qkv_b  = (const float*)d_in[5];
  const float* pp_w   = (const float*)d_in[6];
  const float* pp_b   = (const float*)d_in[7];
  const float* p1_lng = (const float*)d_in[8];
  const float* p1_lnb = (const float*)d_in[9];
  const float* p1_w   = (const float*)d_in[10];
  const float* p1_b   = (const float*)d_in[11];
  const float* p2_lng = (const float*)d_in[12];
  const float* p2_lnb = (const float*)d_in[13];
  const float* p2_w   = (const float*)d_in[14];
  const float* p2_b   = (const float*)d_in[15];
  const float* p3_lng = (const float*)d_in[16];
  const float* p3_lnb = (const float*)d_in[17];
  const float* p3_w   = (const float*)d_in[18];
  const float* p3_b   = (const float*)d_in[19];
  const float* proj_w = (const float*)d_in[20];
  const float* proj_b = (const float*)d_in[21];
  const float* n2_g   = (const float*)d_in[22];
  const float* n2_b   = (const float*)d_in[23];
  const float* fc1_w  = (const float*)d_in[24];
  const float* fc1_b  = (const float*)d_in[25];
  const float* fc2_w  = (const float*)d_in[26];
  const float* fc2_b  = (const float*)d_in[27];
  float* out = (float*)d_out;
  char* ws = (char*)d_ws;

  // workspace layout (bytes)
  u16*   qkvT  = (u16*)  (ws + 0);          // [768][256] bf16
  u16*   projT = (u16*)  (ws + 393216);     // [256][256]
  u16*   fc1T  = (u16*)  (ws + 524288);     // [1024][256]
  u16*   fc2T  = (u16*)  (ws + 1048576);    // [256][1024]
  float* pos   = (float*)(ws + 1572864);    // [3375][8] fp32
  u16*   biasF = (u16*)  (ws + 1703936);    // 2,097,152 bf16
  u16*   xn    = (u16*)  (ws + 5898240);    // [32768][256]
  u16*   yb    = (u16*)  (ws + 22675456);
  u16*   Qb    = (u16*)  (ws + 39452672);   // [64][8][512][32]
  u16*   Kb    = (u16*)  (ws + 56229888);
  u16*   Vtb   = (u16*)  (ws + 73007104);   // [64][8][32][512]
  u16*   attn  = (u16*)  (ws + 89784320);   // [32768][256] window-row order
  float* xres  = (float*)(ws + 106561536);  // [32768][256] fp32   (end 140,115,968)
  u16*   Vn    = xn;     // alias: V (normal layout), xn dead after Q-GEMM
  u16*   hbuf  = xn;     // alias: MLP hidden [32768][1024], spans xn..K (dead by then)
  u16*   x2n   = attn;   // alias: LN2 output, attn dead after proj

  wtr_k<<<768, 256,0,stream>>>(qkv_w, qkvT, 256, 768);
  wtr_k<<<256, 256,0,stream>>>(proj_w, projT, 256, 256);
  wtr_k<<<1024,256,0,stream>>>(fc1_w, fc1T, 256, 1024);
  wtr_k<<<1024,256,0,stream>>>(fc2_w, fc2T, 1024, 256);
  posmlp_k<<<14,256,0,stream>>>(pp_w, pp_b,
                                p1_lng,p1_lnb,p1_w,p1_b,
                                p2_lng,p2_lnb,p2_w,p2_b,
                                p3_lng,p3_lnb,p3_w,p3_b, pos);
  biasx_k<<<8192,256,0,stream>>>(pos, biasF);
  ln_k<<<8192,256,0,stream>>>(x, n1_g, n1_b, xn);
  conv_k<<<2048,256,0,stream>>>(y, yb, 2097152);

  GemmP pq; pq.A=xn; pq.Bt=qkvT; pq.K=256; pq.bvec=qkv_b;
  pq.scale=0.17677669529663687f; pq.add32=nullptr; pq.out32=nullptr; pq.out16=Qb; pq.out16b=nullptr;
  gemm_k<0><<<dim3(256,2),256,0,stream>>>(pq);

  GemmP pkv; pkv.A=yb; pkv.Bt=qkvT + 256*256; pkv.K=256; pkv.bvec=qkv_b + 256;
  pkv.scale=1.f; pkv.add32=nullptr; pkv.out32=nullptr; pkv.out16=Kb; pkv.out16b=Vn;
  gemm_k<1><<<dim3(256,4),256,0,stream>>>(pkv);

  vtr_k<<<512,256,0,stream>>>(Vn, Vtb);
  attn_k<<<512,256,0,stream>>>(Qb, Kb, Vtb, biasF, attn);

  GemmP pp; pp.A=attn; pp.Bt=projT; pp.K=256; pp.bvec=proj_b;
  pp.scale=1.f; pp.add32=x; pp.out32=xres; pp.out16=nullptr; pp.out16b=nullptr;
  gemm_k<2><<<dim3(256,2),256,0,stream>>>(pp);

  ln_k<<<8192,256,0,stream>>>(xres, n2_g, n2_b, x2n);

  GemmP pf1; pf1.A=x2n; pf1.Bt=fc1T; pf1.K=256; pf1.bvec=fc1_b;
  pf1.scale=1.f; pf1.add32=nullptr; pf1.out32=nullptr; pf1.out16=hbuf; pf1.out16b=nullptr;
  gemm_k<3><<<dim3(256,8),256,0,stream>>>(pf1);

  GemmP pf2; pf2.A=hbuf; pf2.Bt=fc2T; pf2.K=1024; pf2.bvec=fc2_b;
  pf2.scale=1.f; pf2.add32=xres; pf2.out32=out; pf2.out16=nullptr; pf2.out16b=nullptr;
  gemm_k<4><<<dim3(256,2),256,0,stream>>>(pf2);
}